// Round 3
// baseline (363.468 us; speedup 1.0000x reference)
//
#include <hip/hip_runtime.h>

// Problem constants (fixed by setup_inputs): B=256, n_regimes=16, d=512.
constexpr int D      = 512;
constexpr int D4     = D / 4;          // float4 columns per row
constexpr int CHUNKS = 8;              // blocks per batch slice
constexpr int BLOCK  = 256;
constexpr int F4_PER_CHUNK = (D * D / 4) / CHUNKS;   // 8192
constexpr int ITERS  = F4_PER_CHUNK / BLOCK;         // 32

// loss = sum_{b,i,j} A[b,i,j] * mask[clip(regime[b])][j] * (regime[b] < n_regimes)
__global__ __launch_bounds__(BLOCK) void iw_loss_kernel(
    const float* __restrict__ A,
    const float* __restrict__ mask,
    const int*  __restrict__ regimes,
    int n_regimes,
    double* __restrict__ ws)
{
    const int b     = blockIdx.x / CHUNKS;
    const int chunk = blockIdx.x % CHUNKS;
    const int tid   = threadIdx.x;

    __shared__ float4 smask[D4];
    const int r = regimes[b];
    const int e = r < 0 ? 0 : (r >= n_regimes ? n_regimes - 1 : r);
    const float v = (r < n_regimes) ? 1.0f : 0.0f;   // validity per reference
    if (tid < D4) {
        float4 m = reinterpret_cast<const float4*>(mask + (size_t)e * D)[tid];
        m.x *= v; m.y *= v; m.z *= v; m.w *= v;
        smask[tid] = m;
    }
    __syncthreads();

    // Each thread's float4-column index is invariant across iterations
    // (stride BLOCK=256 is a multiple of D4=128), so load mask once.
    const float4* A4 = reinterpret_cast<const float4*>(A) + (size_t)b * (D * D / 4);
    const float4 m = smask[tid & (D4 - 1)];

    float acc = 0.0f;
    const int f0 = chunk * F4_PER_CHUNK + tid;
    #pragma unroll
    for (int it = 0; it < ITERS; ++it) {
        const float4 a = A4[f0 + it * BLOCK];
        acc = fmaf(a.x, m.x, acc);
        acc = fmaf(a.y, m.y, acc);
        acc = fmaf(a.z, m.z, acc);
        acc = fmaf(a.w, m.w, acc);
    }

    // wave64 shuffle reduce
    #pragma unroll
    for (int off = 32; off > 0; off >>= 1)
        acc += __shfl_down(acc, off, 64);

    __shared__ double wsum[BLOCK / 64];
    if ((tid & 63) == 0) wsum[tid >> 6] = (double)acc;
    __syncthreads();
    if (tid == 0) {
        double s = 0.0;
        #pragma unroll
        for (int w = 0; w < BLOCK / 64; ++w) s += wsum[w];
        atomicAdd(ws, s);   // global_atomic_add_f64; 2048 adds total, device scope
    }
}

// count = sum_b (regime[b] < n_regimes) * rowsum(mask[clip(regime[b])]);
// out = count > 0 ? loss / count : loss
__global__ __launch_bounds__(256) void iw_finalize_kernel(
    const float* __restrict__ mask,
    const int*  __restrict__ regimes,
    int n_regimes, int B,
    const double* __restrict__ ws,
    float* __restrict__ out)
{
    __shared__ float rowsum[64];
    const int tid = threadIdx.x;

    // 16 lanes per mask row compute its sum (n_regimes <= 16 here)
    const int row = tid >> 4;
    const int seg = tid & 15;
    float s = 0.0f;
    if (row < n_regimes) {
        const float4* m4 = reinterpret_cast<const float4*>(mask + (size_t)row * D);
        #pragma unroll
        for (int k = 0; k < D4 / 16; ++k) {
            const float4 m = m4[seg + k * 16];
            s += m.x + m.y + m.z + m.w;
        }
    }
    #pragma unroll
    for (int off = 8; off > 0; off >>= 1) s += __shfl_down(s, off, 16);
    if (seg == 0 && row < n_regimes) rowsum[row] = s;
    __syncthreads();

    float cf = 0.0f;
    for (int b = tid; b < B; b += 256) {
        const int r = regimes[b];
        if (r < n_regimes) cf += rowsum[r < 0 ? 0 : r];
    }
    #pragma unroll
    for (int off = 32; off > 0; off >>= 1) cf += __shfl_down(cf, off, 64);

    __shared__ double csum[4];
    if ((tid & 63) == 0) csum[tid >> 6] = (double)cf;
    __syncthreads();
    if (tid == 0) {
        const double count = csum[0] + csum[1] + csum[2] + csum[3];
        const double loss  = ws[0];
        out[0] = (float)(count > 0.0 ? loss / count : loss);
    }
}

extern "C" void kernel_launch(void* const* d_in, const int* in_sizes, int n_in,
                              void* d_out, int out_size, void* d_ws, size_t ws_size,
                              hipStream_t stream) {
    const float* A       = (const float*)d_in[0];
    const float* mask    = (const float*)d_in[1];
    const int*   regimes = (const int*)d_in[2];
    const int B          = in_sizes[2];
    const int n_regimes  = in_sizes[1] / D;
    double* ws = (double*)d_ws;

    // d_ws is re-poisoned to 0xAA before every launch — zero the accumulator.
    hipMemsetAsync(d_ws, 0, sizeof(double), stream);
    iw_loss_kernel<<<B * CHUNKS, BLOCK, 0, stream>>>(A, mask, regimes, n_regimes, ws);
    iw_finalize_kernel<<<1, 256, 0, stream>>>(mask, regimes, n_regimes, B, ws,
                                              (float*)d_out);
}

// Round 4
// 334.709 us; speedup vs baseline: 1.0859x; 1.0859x over previous
//
#include <hip/hip_runtime.h>

// Problem constants (fixed by setup_inputs): B=256, n_regimes=16, d=512.
constexpr int D      = 512;
constexpr int D4     = D / 4;          // float4 columns per row
constexpr int CHUNKS = 8;              // blocks per batch slice
constexpr int BLOCK  = 256;
constexpr int F4_PER_CHUNK = (D * D / 4) / CHUNKS;   // 8192 float4 per block
constexpr int ITERS  = F4_PER_CHUNK / BLOCK;         // 32 loads per thread

typedef float f32x4 __attribute__((ext_vector_type(4)));

// partial[blk] = sum over this block's chunk of A[b,i,j] * mask[clip(r_b)][j] * valid_b
// No atomics, no pre-zeroed state: every partial slot is written unconditionally.
__global__ __launch_bounds__(BLOCK) void iw_loss_kernel(
    const float* __restrict__ A,
    const float* __restrict__ mask,
    const int*  __restrict__ regimes,
    int n_regimes,
    double* __restrict__ partial)
{
    const int b     = blockIdx.x / CHUNKS;
    const int chunk = blockIdx.x % CHUNKS;
    const int tid   = threadIdx.x;

    const int r = regimes[b];
    const int e = r < 0 ? 0 : (r >= n_regimes ? n_regimes - 1 : r);
    const float v = (r < n_regimes) ? 1.0f : 0.0f;   // validity per reference

    // Thread's float4-column index is invariant across iterations
    // (stride BLOCK=256 is a multiple of D4=128) -> load mask fragment once.
    f32x4 m = reinterpret_cast<const f32x4*>(mask + (size_t)e * D)[tid & (D4 - 1)];
    m *= v;

    const f32x4* A4 = reinterpret_cast<const f32x4*>(A)
                    + (size_t)b * (D * D / 4) + chunk * F4_PER_CHUNK + tid;

    float acc = 0.0f;
    #pragma unroll
    for (int it = 0; it < ITERS; it += 4) {
        // 4 outstanding 16B/lane streaming loads (nt: A is read exactly once)
        const f32x4 a0 = __builtin_nontemporal_load(A4 + (it + 0) * BLOCK);
        const f32x4 a1 = __builtin_nontemporal_load(A4 + (it + 1) * BLOCK);
        const f32x4 a2 = __builtin_nontemporal_load(A4 + (it + 2) * BLOCK);
        const f32x4 a3 = __builtin_nontemporal_load(A4 + (it + 3) * BLOCK);
        acc = fmaf(a0.x, m.x, acc); acc = fmaf(a0.y, m.y, acc);
        acc = fmaf(a0.z, m.z, acc); acc = fmaf(a0.w, m.w, acc);
        acc = fmaf(a1.x, m.x, acc); acc = fmaf(a1.y, m.y, acc);
        acc = fmaf(a1.z, m.z, acc); acc = fmaf(a1.w, m.w, acc);
        acc = fmaf(a2.x, m.x, acc); acc = fmaf(a2.y, m.y, acc);
        acc = fmaf(a2.z, m.z, acc); acc = fmaf(a2.w, m.w, acc);
        acc = fmaf(a3.x, m.x, acc); acc = fmaf(a3.y, m.y, acc);
        acc = fmaf(a3.z, m.z, acc); acc = fmaf(a3.w, m.w, acc);
    }

    // wave64 shuffle reduce
    #pragma unroll
    for (int off = 32; off > 0; off >>= 1)
        acc += __shfl_down(acc, off, 64);

    __shared__ float wsum[BLOCK / 64];
    if ((tid & 63) == 0) wsum[tid >> 6] = acc;
    __syncthreads();
    if (tid == 0) {
        double s = 0.0;
        #pragma unroll
        for (int w = 0; w < BLOCK / 64; ++w) s += (double)wsum[w];
        partial[blockIdx.x] = s;
    }
}

// loss = sum(partial); count = sum_b valid_b * rowsum(mask[clip(r_b)]);
// out = count > 0 ? loss / count : loss
__global__ __launch_bounds__(256) void iw_finalize_kernel(
    const float* __restrict__ mask,
    const int*  __restrict__ regimes,
    int n_regimes, int B, int n_partial,
    const double* __restrict__ partial,
    float* __restrict__ out)
{
    const int tid = threadIdx.x;

    // --- loss: sum the 2048 block partials (8 per thread) ---
    double ls = 0.0;
    for (int k = tid; k < n_partial; k += 256) ls += partial[k];

    // --- count: 16 lanes per mask row compute its sum (n_regimes <= 16) ---
    __shared__ float rowsum[64];
    const int row = tid >> 4;
    const int seg = tid & 15;
    float s = 0.0f;
    if (row < n_regimes) {
        const f32x4* m4 = reinterpret_cast<const f32x4*>(mask + (size_t)row * D);
        #pragma unroll
        for (int k = 0; k < D4 / 16; ++k) {
            const f32x4 m = m4[seg + k * 16];
            s += m.x + m.y + m.z + m.w;
        }
    }
    #pragma unroll
    for (int off = 8; off > 0; off >>= 1) s += __shfl_down(s, off, 16);
    if (seg == 0 && row < n_regimes) rowsum[row] = s;
    __syncthreads();

    float cf = 0.0f;
    for (int b = tid; b < B; b += 256) {
        const int r = regimes[b];
        if (r < n_regimes) cf += rowsum[r < 0 ? 0 : r];
    }

    // --- block reduce both (4 waves) ---
    #pragma unroll
    for (int off = 32; off > 0; off >>= 1) {
        ls += __shfl_down(ls, off, 64);
        cf += __shfl_down(cf, off, 64);
    }
    __shared__ double lsum[4];
    __shared__ float  csum[4];
    if ((tid & 63) == 0) { lsum[tid >> 6] = ls; csum[tid >> 6] = cf; }
    __syncthreads();
    if (tid == 0) {
        const double loss  = lsum[0] + lsum[1] + lsum[2] + lsum[3];
        const double count = (double)csum[0] + csum[1] + csum[2] + csum[3];
        out[0] = (float)(count > 0.0 ? loss / count : loss);
    }
}

extern "C" void kernel_launch(void* const* d_in, const int* in_sizes, int n_in,
                              void* d_out, int out_size, void* d_ws, size_t ws_size,
                              hipStream_t stream) {
    const float* A       = (const float*)d_in[0];
    const float* mask    = (const float*)d_in[1];
    const int*   regimes = (const int*)d_in[2];
    const int B          = in_sizes[2];
    const int n_regimes  = in_sizes[1] / D;
    double* partial = (double*)d_ws;          // 2048 doubles, all written each call

    const int nblocks = B * CHUNKS;
    iw_loss_kernel<<<nblocks, BLOCK, 0, stream>>>(A, mask, regimes, n_regimes, partial);
    iw_finalize_kernel<<<1, 256, 0, stream>>>(mask, regimes, n_regimes, B, nblocks,
                                              partial, (float*)d_out);
}